// Round 15
// baseline (369.262 us; speedup 1.0000x reference)
//
#include <hip/hip_runtime.h>
#include <hip/hip_fp16.h>

#define H 32
#define TPB 256
#define TPB_P 256         // threads for place
#define TPB2 256          // threads for streaming accumulate
#define EPT 16            // edges per thread in place (4096 edges per WG)
#define SLOTS 128         // dst slots per bucket
#define CAP 2048          // fixed capacity per bucket (mean 1280, +21 sigma)
#define MAXBUCK 2048      // static LDS bound (actual NBUCK = 1563)

// ---------------- encoder: thread = node, vectorized loads, W broadcast from LDS ------
// nodes [0,NB) = bridge (FIN=16), [NB,NB+NR) = road (FIN=8). Also inits gcurp.
__global__ void __launch_bounds__(TPB) encoder_kernel(
        const float* __restrict__ x_b, const float* __restrict__ x_r,
        const float* __restrict__ W_b, const float* __restrict__ b_b,
        const float* __restrict__ W_r, const float* __restrict__ b_r,
        __half* __restrict__ h_b16, __half* __restrict__ h_r16,
        int NB, int NR,
        int* __restrict__ gcurp, int NBUCK) {
    int gid = blockIdx.x * TPB + threadIdx.x;
    if (gid < NBUCK) gcurp[gid * 16] = gid * CAP;

    __shared__ float sWb[16][H];
    __shared__ float sWr8[8][H];
    __shared__ float sbb[H];
    __shared__ float sbr[H];
    int t = threadIdx.x;
    for (int i = t; i < 16 * H; i += TPB) ((float*)sWb)[i] = W_b[i];
    for (int i = t; i < 8 * H; i += TPB) ((float*)sWr8)[i] = W_r[i];
    if (t < H) { sbb[t] = b_b[t]; sbr[t] = b_r[t]; }
    __syncthreads();

    long long node = gid;
    if (node < NB) {
        const float4* px = (const float4*)(x_b + node * 16);
        float acc[H];
        #pragma unroll
        for (int j = 0; j < H; ++j) acc[j] = sbb[j];
        #pragma unroll
        for (int c = 0; c < 4; ++c) {
            float4 q = px[c];
            float xs[4] = {q.x, q.y, q.z, q.w};
            #pragma unroll
            for (int u = 0; u < 4; ++u) {
                int k = c * 4 + u;
                #pragma unroll
                for (int j = 0; j < H; ++j)
                    acc[j] = fmaf(xs[u], sWb[k][j], acc[j]);
            }
        }
        __half2 o[H / 2];
        #pragma unroll
        for (int j2 = 0; j2 < H / 2; ++j2)
            o[j2] = __floats2half2_rn(fmaxf(acc[2 * j2], 0.0f), fmaxf(acc[2 * j2 + 1], 0.0f));
        float4* dst = (float4*)(h_b16 + node * H);
        const float4* src = (const float4*)o;
        dst[0] = src[0]; dst[1] = src[1]; dst[2] = src[2]; dst[3] = src[3];
    } else if (node < (long long)NB + NR) {
        long long m = node - NB;
        const float4* px = (const float4*)(x_r + m * 8);
        float acc[H];
        #pragma unroll
        for (int j = 0; j < H; ++j) acc[j] = sbr[j];
        #pragma unroll
        for (int c = 0; c < 2; ++c) {
            float4 q = px[c];
            float xs[4] = {q.x, q.y, q.z, q.w};
            #pragma unroll
            for (int u = 0; u < 4; ++u) {
                int k = c * 4 + u;
                #pragma unroll
                for (int j = 0; j < H; ++j)
                    acc[j] = fmaf(xs[u], sWr8[k][j], acc[j]);
            }
        }
        __half2 o[H / 2];
        #pragma unroll
        for (int j2 = 0; j2 < H / 2; ++j2)
            o[j2] = __floats2half2_rn(fmaxf(acc[2 * j2], 0.0f), fmaxf(acc[2 * j2 + 1], 0.0f));
        float4* dst = (float4*)(h_r16 + m * H);
        const float4* src = (const float4*)o;
        dst[0] = src[0]; dst[1] = src[1]; dst[2] = src[2]; dst[3] = src[3];
    }
}

// ---------------- place edges into fixed-capacity bucket bins ----------------
__global__ void __launch_bounds__(TPB_P) place_kernel(
        const int* __restrict__ src_rb, const int* __restrict__ dst_rb,
        const int* __restrict__ src_bb, const int* __restrict__ dst_bb,
        int* __restrict__ gcurp, int* __restrict__ bins,
        int E_RB, int E_BB, int NB, int NBUCK) {
    __shared__ int lcnt[MAXBUCK];
    __shared__ int wbase[MAXBUCK];
    int t = threadIdx.x;
    for (int i = t; i < MAXBUCK; i += TPB_P) lcnt[i] = 0;
    __syncthreads();
    long long e0 = (long long)blockIdx.x * (TPB_P * EPT);
    long long EA = (long long)E_RB + E_BB;
    int bk[EPT], loc[EPT], pk[EPT];
    #pragma unroll
    for (int j = 0; j < EPT; ++j) {
        long long e = e0 + j * TPB_P + t;
        bk[j] = -1; loc[j] = 0; pk[j] = 0;
        if (e < EA) {
            int s, d;
            if (e < E_RB) { s = src_rb[e]; d = dst_rb[e]; }
            else          { long long e2 = e - E_RB; s = src_bb[e2]; d = NB + dst_bb[e2]; }
            bk[j] = d >> 7;
            pk[j] = (s << 7) | (d & 127);
            loc[j] = atomicAdd(&lcnt[bk[j]], 1);
        }
    }
    __syncthreads();
    for (int i = t; i < NBUCK; i += TPB_P) {
        int c = lcnt[i];
        wbase[i] = c ? atomicAdd(&gcurp[i * 16], c) : 0;
    }
    __syncthreads();
    #pragma unroll
    for (int j = 0; j < EPT; ++j) {
        if (bk[j] >= 0) {
            int gslot = wbase[bk[j]] + loc[j];
            if (gslot < (bk[j] + 1) * CAP)      // overflow guard (never fires)
                bins[gslot] = pk[j];
        }
    }
}

// ---------------- streaming accumulate: one pass, LDS fp32 atomics ----------------
// One WG per bucket of 128 slots. No sort, no scan: every wave streams edges,
// gathers the 64B fp16 row, and atomically accumulates into padded LDS.
__global__ void __launch_bounds__(TPB2) buildgather_kernel(
        const __half* __restrict__ h_r16, const __half* __restrict__ h_b16,
        const int* __restrict__ bins, const int* __restrict__ gcurp,
        __half* __restrict__ mean16, int NB, int N2) {
    __shared__ float acc[SLOTS * 33];    // padded stride 33 -> conflict-free  (16.9 KB)
    __shared__ int   scnt[SLOTS];
    int t = threadIdx.x;
    int b = blockIdx.x;
    int start = b * CAP;
    int n = gcurp[b * 16] - start;       // final count for this bucket
    if (n > CAP) n = CAP;

    for (int i = t; i < SLOTS * 33; i += TPB2) acc[i] = 0.0f;
    if (t < SLOTS) scnt[t] = 0;
    __syncthreads();

    // streaming accumulate: 16-lane group per edge, 4 edges in flight
    int lane = t & 15, g = t >> 4;       // 16 groups
    long long base_slot = (long long)b << 7;
    for (int e = g; e < n; e += 64) {
        int pk[4];
        #pragma unroll
        for (int u = 0; u < 4; ++u) {
            int idx = e + u * 16;
            pk[u] = (idx < n) ? bins[start + idx] : -1;
        }
        float2 f[4];
        #pragma unroll
        for (int u = 0; u < 4; ++u) {
            if (pk[u] >= 0) {
                int s = pk[u] >> 7;
                long long gd0 = base_slot + (pk[u] & 127);
                const __half* __restrict__ hs = (gd0 < NB) ? h_r16 : h_b16;
                f[u] = __half22float2(*(const __half2*)(hs + (long long)s * H + 2 * lane));
            }
        }
        #pragma unroll
        for (int u = 0; u < 4; ++u) {
            if (pk[u] >= 0) {
                int dloc = pk[u] & 127;
                atomicAdd(&acc[dloc * 33 + 2 * lane], f[u].x);
                atomicAdd(&acc[dloc * 33 + 2 * lane + 1], f[u].y);
                if (lane == 0) atomicAdd(&scnt[dloc], 1);
            }
        }
    }
    __syncthreads();

    // finalize: 16-lane group per slot, half2 write
    for (int sl = g; sl < SLOTS; sl += 16) {
        long long gd = base_slot + sl;
        if (gd >= N2) break;
        float inv = 1.0f / fmaxf((float)scnt[sl], 1.0f);
        float ax = acc[sl * 33 + 2 * lane] * inv;
        float ay = acc[sl * 33 + 2 * lane + 1] * inv;
        *(__half2*)(mean16 + gd * H + 2 * lane) = __floats2half2_rn(ax, ay);
    }
}

// ---------------- fused head (thread = node, fp16 inputs, W broadcast from LDS) ----------
__global__ void __launch_bounds__(TPB) head_kernel(
        const __half* __restrict__ h_b16,
        const __half* __restrict__ mean16,   // [2NB, H]
        const float* __restrict__ Wl_rb,
        const float* __restrict__ bl_rb,
        const float* __restrict__ Wl_bb,
        const float* __restrict__ bl_bb,
        const float* __restrict__ Wr_rb,
        const float* __restrict__ Wr_bb,
        const float* __restrict__ Wo,
        const float* __restrict__ bo,
        float* __restrict__ y, int N) {
    __shared__ float sWl_rb[H][H];
    __shared__ float sWl_bb[H][H];
    __shared__ float sWr[H][H];
    __shared__ float sbl[H];
    __shared__ float sWo[H];
    __shared__ float sbo;

    int t = threadIdx.x;
    for (int i = t; i < H * H; i += blockDim.x) {
        ((float*)sWl_rb)[i] = Wl_rb[i];
        ((float*)sWl_bb)[i] = Wl_bb[i];
        ((float*)sWr)[i]    = Wr_rb[i] + Wr_bb[i];
    }
    if (t < H) {
        sbl[t] = bl_rb[t] + bl_bb[t];
        sWo[t] = Wo[t];
    }
    if (t == 0) sbo = bo[0];
    __syncthreads();

    int node = blockIdx.x * TPB + t;
    if (node >= N) return;

    const float4* pr = (const float4*)(mean16 + (long long)node * H);
    const float4* pb = (const float4*)(mean16 + ((long long)N + node) * H);
    const float4* ph = (const float4*)(h_b16 + (long long)node * H);

    float acc[H];
    #pragma unroll
    for (int j = 0; j < H; ++j) acc[j] = sbl[j];

    #pragma unroll
    for (int c = 0; c < 4; ++c) {            // 8 k-values per chunk
        float4 qr = pr[c];
        float4 qb = pb[c];
        float4 qh = ph[c];
        const __half2* hr = (const __half2*)&qr;
        const __half2* hb = (const __half2*)&qb;
        const __half2* hh = (const __half2*)&qh;
        #pragma unroll
        for (int u = 0; u < 4; ++u) {
            float2 fr = __half22float2(hr[u]);
            float2 fb = __half22float2(hb[u]);
            float2 fh = __half22float2(hh[u]);
            int k0 = c * 8 + u * 2;
            #pragma unroll
            for (int j = 0; j < H; ++j) {
                acc[j] = fmaf(fr.x, sWl_rb[k0][j], acc[j]);
                acc[j] = fmaf(fb.x, sWl_bb[k0][j], acc[j]);
                acc[j] = fmaf(fh.x, sWr[k0][j], acc[j]);
                acc[j] = fmaf(fr.y, sWl_rb[k0 + 1][j], acc[j]);
                acc[j] = fmaf(fb.y, sWl_bb[k0 + 1][j], acc[j]);
                acc[j] = fmaf(fh.y, sWr[k0 + 1][j], acc[j]);
            }
        }
    }

    float out = 0.0f;
    #pragma unroll
    for (int j = 0; j < H; ++j)
        out = fmaf(fmaxf(acc[j], 0.0f), sWo[j], out);
    y[node] = out + sbo;
}

extern "C" void kernel_launch(void* const* d_in, const int* in_sizes, int n_in,
                              void* d_out, int out_size, void* d_ws, size_t ws_size,
                              hipStream_t stream) {
    const float* x_bridge = (const float*)d_in[0];
    const float* x_road   = (const float*)d_in[1];
    const int* src_rb = (const int*)d_in[4];
    const int* dst_rb = (const int*)d_in[5];
    const int* src_bb = (const int*)d_in[6];
    const int* dst_bb = (const int*)d_in[7];
    const float* W_enc_b = (const float*)d_in[8];
    const float* b_enc_b = (const float*)d_in[9];
    const float* W_enc_r = (const float*)d_in[10];
    const float* b_enc_r = (const float*)d_in[11];
    const float* Wl_rb = (const float*)d_in[15];
    const float* bl_rb = (const float*)d_in[16];
    const float* Wr_rb = (const float*)d_in[17];
    const float* Wl_bb = (const float*)d_in[18];
    const float* bl_bb = (const float*)d_in[19];
    const float* Wr_bb = (const float*)d_in[20];
    const float* Wo = (const float*)d_in[21];
    const float* bo = (const float*)d_in[22];
    float* y = (float*)d_out;

    const int NB = in_sizes[0] / 16;
    const int NR = in_sizes[1] / 8;
    const int E_RB = in_sizes[4];
    const int E_BB = in_sizes[6];
    const int N2 = 2 * NB;
    const long long E_ALL = (long long)E_RB + E_BB;
    const int NBUCK = (N2 + SLOTS - 1) / SLOTS;     // 1563

    // Workspace layout (~45 MB)
    char* wp = (char*)d_ws;
    __half* h_r16  = (__half*)wp; wp += (size_t)NR * H * sizeof(__half);
    __half* h_b16  = (__half*)wp; wp += (size_t)NB * H * sizeof(__half);
    __half* mean16 = (__half*)wp; wp += (size_t)N2 * H * sizeof(__half);
    int* bins  = (int*)wp;       wp += (size_t)NBUCK * CAP * sizeof(int);
    int* gcurp = (int*)wp;       wp += (size_t)NBUCK * 16 * sizeof(int);

    // thread-per-node encoder (both node types) + gcurp cursor init
    {
        long long nodes = (long long)NB + NR;
        int blocks = (int)((nodes + TPB - 1) / TPB);
        encoder_kernel<<<blocks, TPB, 0, stream>>>(x_bridge, x_road,
                                                   W_enc_b, b_enc_b, W_enc_r, b_enc_r,
                                                   h_b16, h_r16, NB, NR, gcurp, NBUCK);
    }

    // single edge pass: place into fixed-capacity bucket bins
    int nWGe = (int)((E_ALL + (TPB_P * EPT) - 1) / (TPB_P * EPT));   // 367
    place_kernel<<<nWGe, TPB_P, 0, stream>>>(src_rb, dst_rb, src_bb, dst_bb,
                                             gcurp, bins, E_RB, E_BB, NB, NBUCK);

    // streaming LDS-atomic accumulate -> mean16
    buildgather_kernel<<<NBUCK, TPB2, 0, stream>>>(h_r16, h_b16, bins, gcurp,
                                                   mean16, NB, N2);

    // fused head
    head_kernel<<<(NB + TPB - 1) / TPB, TPB, 0, stream>>>(h_b16, mean16,
                                                  Wl_rb, bl_rb, Wl_bb, bl_bb,
                                                  Wr_rb, Wr_bb, Wo, bo, y, NB);
}

// Round 16
// 97.018 us; speedup vs baseline: 3.8061x; 3.8061x over previous
//
#include <hip/hip_runtime.h>
#include <hip/hip_fp16.h>

#define H 32
#define TPB 256
#define EPT 16            // edges per thread in place (4096 edges per WG)
#define SLOTS 128         // dst slots per bucket
#define CAP 2048          // fixed capacity per bucket (mean 1280, +21 sigma)
#define MAXBUCK 2048      // static LDS bound (actual NBUCK = 1563)

// ---------------- prep: heterogeneous kernel -----------------------------------------
// Blocks [0, encBlocks): encoder (thread = node; [0,NB)=bridge FIN=16, then road FIN=8).
// Blocks [encBlocks, encBlocks+placeBlocks): place edges into fixed-cap bucket bins.
// gcurp must be zeroed before launch (cursors are bucket-relative).
__global__ void __launch_bounds__(TPB) prep_kernel(
        // encoder args
        const float* __restrict__ x_b, const float* __restrict__ x_r,
        const float* __restrict__ W_b, const float* __restrict__ b_b,
        const float* __restrict__ W_r, const float* __restrict__ b_r,
        __half* __restrict__ h_b16, __half* __restrict__ h_r16,
        int NB, int NR, int encBlocks,
        // place args
        const int* __restrict__ src_rb, const int* __restrict__ dst_rb,
        const int* __restrict__ src_bb, const int* __restrict__ dst_bb,
        int* __restrict__ gcurp, int* __restrict__ bins,
        int E_RB, int E_BB, int NBUCK) {
    int t = threadIdx.x;

    if (blockIdx.x < encBlocks) {
        // ---------------- encoder part ----------------
        __shared__ float sWb[16][H];
        __shared__ float sWr8[8][H];
        __shared__ float sbb[H];
        __shared__ float sbr[H];
        for (int i = t; i < 16 * H; i += TPB) ((float*)sWb)[i] = W_b[i];
        for (int i = t; i < 8 * H; i += TPB) ((float*)sWr8)[i] = W_r[i];
        if (t < H) { sbb[t] = b_b[t]; sbr[t] = b_r[t]; }
        __syncthreads();

        long long node = (long long)blockIdx.x * TPB + t;
        if (node < NB) {
            const float4* px = (const float4*)(x_b + node * 16);
            float acc[H];
            #pragma unroll
            for (int j = 0; j < H; ++j) acc[j] = sbb[j];
            #pragma unroll
            for (int c = 0; c < 4; ++c) {
                float4 q = px[c];
                float xs[4] = {q.x, q.y, q.z, q.w};
                #pragma unroll
                for (int u = 0; u < 4; ++u) {
                    int k = c * 4 + u;
                    #pragma unroll
                    for (int j = 0; j < H; ++j)
                        acc[j] = fmaf(xs[u], sWb[k][j], acc[j]);
                }
            }
            __half2 o[H / 2];
            #pragma unroll
            for (int j2 = 0; j2 < H / 2; ++j2)
                o[j2] = __floats2half2_rn(fmaxf(acc[2 * j2], 0.0f), fmaxf(acc[2 * j2 + 1], 0.0f));
            float4* dst = (float4*)(h_b16 + node * H);
            const float4* src = (const float4*)o;
            dst[0] = src[0]; dst[1] = src[1]; dst[2] = src[2]; dst[3] = src[3];
        } else if (node < (long long)NB + NR) {
            long long m = node - NB;
            const float4* px = (const float4*)(x_r + m * 8);
            float acc[H];
            #pragma unroll
            for (int j = 0; j < H; ++j) acc[j] = sbr[j];
            #pragma unroll
            for (int c = 0; c < 2; ++c) {
                float4 q = px[c];
                float xs[4] = {q.x, q.y, q.z, q.w};
                #pragma unroll
                for (int u = 0; u < 4; ++u) {
                    int k = c * 4 + u;
                    #pragma unroll
                    for (int j = 0; j < H; ++j)
                        acc[j] = fmaf(xs[u], sWr8[k][j], acc[j]);
                }
            }
            __half2 o[H / 2];
            #pragma unroll
            for (int j2 = 0; j2 < H / 2; ++j2)
                o[j2] = __floats2half2_rn(fmaxf(acc[2 * j2], 0.0f), fmaxf(acc[2 * j2 + 1], 0.0f));
            float4* dst = (float4*)(h_r16 + m * H);
            const float4* src = (const float4*)o;
            dst[0] = src[0]; dst[1] = src[1]; dst[2] = src[2]; dst[3] = src[3];
        }
    } else {
        // ---------------- place part ----------------
        __shared__ int lcnt[MAXBUCK];
        __shared__ int wbase[MAXBUCK];
        for (int i = t; i < MAXBUCK; i += TPB) lcnt[i] = 0;
        __syncthreads();
        long long e0 = (long long)(blockIdx.x - encBlocks) * (TPB * EPT);
        long long EA = (long long)E_RB + E_BB;
        int bk[EPT], loc[EPT], pk[EPT];
        #pragma unroll
        for (int j = 0; j < EPT; ++j) {
            long long e = e0 + j * TPB + t;
            bk[j] = -1; loc[j] = 0; pk[j] = 0;
            if (e < EA) {
                int s, d;
                if (e < E_RB) { s = src_rb[e]; d = dst_rb[e]; }
                else          { long long e2 = e - E_RB; s = src_bb[e2]; d = NB + dst_bb[e2]; }
                bk[j] = d >> 7;
                pk[j] = (s << 7) | (d & 127);
                loc[j] = atomicAdd(&lcnt[bk[j]], 1);
            }
        }
        __syncthreads();
        for (int i = t; i < NBUCK; i += TPB) {
            int c = lcnt[i];
            wbase[i] = c ? (i * CAP + atomicAdd(&gcurp[i * 16], c)) : 0;
        }
        __syncthreads();
        #pragma unroll
        for (int j = 0; j < EPT; ++j) {
            if (bk[j] >= 0) {
                int gslot = wbase[bk[j]] + loc[j];
                if (gslot < (bk[j] + 1) * CAP)      // overflow guard (never fires)
                    bins[gslot] = pk[j];
            }
        }
    }
}

// ---------------- fused build+gather: int4 bins read, sort, unroll-8 gather ----------
__global__ void __launch_bounds__(TPB) buildgather_kernel(
        const __half* __restrict__ h_r16, const __half* __restrict__ h_b16,
        const int* __restrict__ bins, const int* __restrict__ gcurp,
        __half* __restrict__ mean16, int NB, int N2) {
    __shared__ int rawbuf[CAP];          // 8 KB  (bucket's packed edges)
    __shared__ int srcbuf[CAP];          // 8 KB  (slot-sorted srcs)
    __shared__ int lcnt[SLOTS];
    __shared__ int lbase[SLOTS];
    __shared__ int lcur[SLOTS];
    __shared__ int tmp[SLOTS];
    int t = threadIdx.x;
    int b = blockIdx.x;
    int start = b * CAP;                 // CAP multiple of 4 -> int4-aligned
    int n = gcurp[b * 16];               // relative count for this bucket
    if (n > CAP) n = CAP;

    if (t < SLOTS) lcnt[t] = 0;
    __syncthreads();

    // phase A: int4 read of bins into LDS + per-slot histogram
    {
        int n4 = n >> 2;
        const int4* bins4 = (const int4*)(bins + start);
        for (int i = t; i < n4; i += TPB) {
            int4 p = bins4[i];
            ((int4*)rawbuf)[i] = p;
            atomicAdd(&lcnt[p.x & 127], 1);
            atomicAdd(&lcnt[p.y & 127], 1);
            atomicAdd(&lcnt[p.z & 127], 1);
            atomicAdd(&lcnt[p.w & 127], 1);
        }
        for (int i = (n4 << 2) + t; i < n; i += TPB) {
            int packed = bins[start + i];
            rawbuf[i] = packed;
            atomicAdd(&lcnt[packed & 127], 1);
        }
    }
    __syncthreads();

    // phase B: exclusive scan of 128 slot counters
    if (t < SLOTS) tmp[t] = lcnt[t];
    __syncthreads();
    for (int off = 1; off < SLOTS; off <<= 1) {
        int x = (t >= off && t < SLOTS) ? tmp[t - off] : 0;
        __syncthreads();
        if (t < SLOTS) tmp[t] += x;
        __syncthreads();
    }
    if (t < SLOTS) { lbase[t] = tmp[t] - lcnt[t]; lcur[t] = tmp[t] - lcnt[t]; }
    __syncthreads();

    // phase C: LDS->LDS scatter, slot-sorted
    for (int i = t; i < n; i += TPB) {
        int packed = rawbuf[i];
        int slot = atomicAdd(&lcur[packed & 127], 1);
        srcbuf[slot] = packed >> 7;
    }
    __syncthreads();

    // phase D: gather; 16 groups of 16 lanes; lane owns channels {2l,2l+1}; 8/4/1 ILP
    int lane = t & 15, g = t >> 4;
    long long base_slot = (long long)b << 7;
    for (int sl = g; sl < SLOTS; sl += (TPB / 16)) {
        long long gd = base_slot + sl;
        if (gd >= N2) break;
        const __half* __restrict__ hs = (gd < NB) ? h_r16 : h_b16;
        int off = lbase[sl];
        int cnt = lcnt[sl];
        float ax = 0.0f, ay = 0.0f;
        int k = 0;
        for (; k + 8 <= cnt; k += 8) {
            int s[8];
            #pragma unroll
            for (int j = 0; j < 8; ++j) s[j] = srcbuf[off + k + j];
            float2 f[8];
            #pragma unroll
            for (int j = 0; j < 8; ++j)
                f[j] = __half22float2(*(const __half2*)(hs + (long long)s[j] * H + 2 * lane));
            #pragma unroll
            for (int j = 0; j < 8; ++j) { ax += f[j].x; ay += f[j].y; }
        }
        if (k + 4 <= cnt) {
            int s[4];
            #pragma unroll
            for (int j = 0; j < 4; ++j) s[j] = srcbuf[off + k + j];
            float2 f[4];
            #pragma unroll
            for (int j = 0; j < 4; ++j)
                f[j] = __half22float2(*(const __half2*)(hs + (long long)s[j] * H + 2 * lane));
            #pragma unroll
            for (int j = 0; j < 4; ++j) { ax += f[j].x; ay += f[j].y; }
            k += 4;
        }
        for (; k < cnt; ++k) {
            int s = srcbuf[off + k];
            float2 f = __half22float2(*(const __half2*)(hs + (long long)s * H + 2 * lane));
            ax += f.x; ay += f.y;
        }
        float inv = 1.0f / fmaxf((float)cnt, 1.0f);
        *(__half2*)(mean16 + gd * H + 2 * lane) = __floats2half2_rn(ax * inv, ay * inv);
    }
}

// ---------------- fused head (thread = node, fp16 inputs, W broadcast from LDS) ----------
__global__ void __launch_bounds__(TPB) head_kernel(
        const __half* __restrict__ h_b16,
        const __half* __restrict__ mean16,   // [2NB, H]
        const float* __restrict__ Wl_rb,
        const float* __restrict__ bl_rb,
        const float* __restrict__ Wl_bb,
        const float* __restrict__ bl_bb,
        const float* __restrict__ Wr_rb,
        const float* __restrict__ Wr_bb,
        const float* __restrict__ Wo,
        const float* __restrict__ bo,
        float* __restrict__ y, int N) {
    __shared__ float sWl_rb[H][H];
    __shared__ float sWl_bb[H][H];
    __shared__ float sWr[H][H];
    __shared__ float sbl[H];
    __shared__ float sWo[H];
    __shared__ float sbo;

    int t = threadIdx.x;
    for (int i = t; i < H * H; i += blockDim.x) {
        ((float*)sWl_rb)[i] = Wl_rb[i];
        ((float*)sWl_bb)[i] = Wl_bb[i];
        ((float*)sWr)[i]    = Wr_rb[i] + Wr_bb[i];
    }
    if (t < H) {
        sbl[t] = bl_rb[t] + bl_bb[t];
        sWo[t] = Wo[t];
    }
    if (t == 0) sbo = bo[0];
    __syncthreads();

    int node = blockIdx.x * TPB + t;
    if (node >= N) return;

    const float4* pr = (const float4*)(mean16 + (long long)node * H);
    const float4* pb = (const float4*)(mean16 + ((long long)N + node) * H);
    const float4* ph = (const float4*)(h_b16 + (long long)node * H);

    float acc[H];
    #pragma unroll
    for (int j = 0; j < H; ++j) acc[j] = sbl[j];

    #pragma unroll
    for (int c = 0; c < 4; ++c) {            // 8 k-values per chunk
        float4 qr = pr[c];
        float4 qb = pb[c];
        float4 qh = ph[c];
        const __half2* hr = (const __half2*)&qr;
        const __half2* hb = (const __half2*)&qb;
        const __half2* hh = (const __half2*)&qh;
        #pragma unroll
        for (int u = 0; u < 4; ++u) {
            float2 fr = __half22float2(hr[u]);
            float2 fb = __half22float2(hb[u]);
            float2 fh = __half22float2(hh[u]);
            int k0 = c * 8 + u * 2;
            #pragma unroll
            for (int j = 0; j < H; ++j) {
                acc[j] = fmaf(fr.x, sWl_rb[k0][j], acc[j]);
                acc[j] = fmaf(fb.x, sWl_bb[k0][j], acc[j]);
                acc[j] = fmaf(fh.x, sWr[k0][j], acc[j]);
                acc[j] = fmaf(fr.y, sWl_rb[k0 + 1][j], acc[j]);
                acc[j] = fmaf(fb.y, sWl_bb[k0 + 1][j], acc[j]);
                acc[j] = fmaf(fh.y, sWr[k0 + 1][j], acc[j]);
            }
        }
    }

    float out = 0.0f;
    #pragma unroll
    for (int j = 0; j < H; ++j)
        out = fmaf(fmaxf(acc[j], 0.0f), sWo[j], out);
    y[node] = out + sbo;
}

extern "C" void kernel_launch(void* const* d_in, const int* in_sizes, int n_in,
                              void* d_out, int out_size, void* d_ws, size_t ws_size,
                              hipStream_t stream) {
    const float* x_bridge = (const float*)d_in[0];
    const float* x_road   = (const float*)d_in[1];
    const int* src_rb = (const int*)d_in[4];
    const int* dst_rb = (const int*)d_in[5];
    const int* src_bb = (const int*)d_in[6];
    const int* dst_bb = (const int*)d_in[7];
    const float* W_enc_b = (const float*)d_in[8];
    const float* b_enc_b = (const float*)d_in[9];
    const float* W_enc_r = (const float*)d_in[10];
    const float* b_enc_r = (const float*)d_in[11];
    const float* Wl_rb = (const float*)d_in[15];
    const float* bl_rb = (const float*)d_in[16];
    const float* Wr_rb = (const float*)d_in[17];
    const float* Wl_bb = (const float*)d_in[18];
    const float* bl_bb = (const float*)d_in[19];
    const float* Wr_bb = (const float*)d_in[20];
    const float* Wo = (const float*)d_in[21];
    const float* bo = (const float*)d_in[22];
    float* y = (float*)d_out;

    const int NB = in_sizes[0] / 16;
    const int NR = in_sizes[1] / 8;
    const int E_RB = in_sizes[4];
    const int E_BB = in_sizes[6];
    const int N2 = 2 * NB;
    const long long E_ALL = (long long)E_RB + E_BB;
    const int NBUCK = (N2 + SLOTS - 1) / SLOTS;     // 1563

    // Workspace layout (~45 MB)
    char* wp = (char*)d_ws;
    __half* h_r16  = (__half*)wp; wp += (size_t)NR * H * sizeof(__half);
    __half* h_b16  = (__half*)wp; wp += (size_t)NB * H * sizeof(__half);
    __half* mean16 = (__half*)wp; wp += (size_t)N2 * H * sizeof(__half);
    int* bins  = (int*)wp;       wp += (size_t)NBUCK * CAP * sizeof(int);
    int* gcurp = (int*)wp;       wp += (size_t)NBUCK * 16 * sizeof(int);

    // zero the bucket cursors (relative counts), then run encoder || place
    hipMemsetAsync(gcurp, 0, (size_t)NBUCK * 16 * sizeof(int), stream);

    long long nodes = (long long)NB + NR;
    int encBlocks = (int)((nodes + TPB - 1) / TPB);                      // 1172
    int placeBlocks = (int)((E_ALL + (TPB * EPT) - 1) / (TPB * EPT));    // 367
    prep_kernel<<<encBlocks + placeBlocks, TPB, 0, stream>>>(
        x_bridge, x_road, W_enc_b, b_enc_b, W_enc_r, b_enc_r,
        h_b16, h_r16, NB, NR, encBlocks,
        src_rb, dst_rb, src_bb, dst_bb, gcurp, bins, E_RB, E_BB, NBUCK);

    // fused per-bucket slot-sort (LDS) + gather -> mean16
    buildgather_kernel<<<NBUCK, TPB, 0, stream>>>(h_r16, h_b16, bins, gcurp,
                                                  mean16, NB, N2);

    // fused head
    head_kernel<<<(NB + TPB - 1) / TPB, TPB, 0, stream>>>(h_b16, mean16,
                                                  Wl_rb, bl_rb, Wl_bb, bl_bb,
                                                  Wr_rb, Wr_bb, Wo, bo, y, NB);
}

// Round 17
// 95.230 us; speedup vs baseline: 3.8776x; 1.0188x over previous
//
#include <hip/hip_runtime.h>
#include <hip/hip_fp16.h>

#define H 32
#define TPB 256
#define EPT 32            // edges per thread in place (8192 edges per WG)
#define SLOTS 128         // dst slots per bucket
#define CAP 2048          // fixed capacity per bucket (mean 1280, +21 sigma)
#define MAXBUCK 2048      // static LDS bound (actual NBUCK = 1563)

// ---------------- prep: heterogeneous kernel -----------------------------------------
// Blocks [0, encBlocks): encoder (thread = node).
// Blocks [encBlocks, ...): place edges into fixed-cap bucket bins (relative cursors;
// gcurp must be zeroed before launch).
__global__ void __launch_bounds__(TPB) prep_kernel(
        // encoder args
        const float* __restrict__ x_b, const float* __restrict__ x_r,
        const float* __restrict__ W_b, const float* __restrict__ b_b,
        const float* __restrict__ W_r, const float* __restrict__ b_r,
        __half* __restrict__ h_b16, __half* __restrict__ h_r16,
        int NB, int NR, int encBlocks,
        // place args
        const int* __restrict__ src_rb, const int* __restrict__ dst_rb,
        const int* __restrict__ src_bb, const int* __restrict__ dst_bb,
        int* __restrict__ gcurp, int* __restrict__ bins,
        int E_RB, int E_BB, int NBUCK) {
    int t = threadIdx.x;

    if (blockIdx.x < encBlocks) {
        // ---------------- encoder part ----------------
        __shared__ float sWb[16][H];
        __shared__ float sWr8[8][H];
        __shared__ float sbb[H];
        __shared__ float sbr[H];
        for (int i = t; i < 16 * H; i += TPB) ((float*)sWb)[i] = W_b[i];
        for (int i = t; i < 8 * H; i += TPB) ((float*)sWr8)[i] = W_r[i];
        if (t < H) { sbb[t] = b_b[t]; sbr[t] = b_r[t]; }
        __syncthreads();

        long long node = (long long)blockIdx.x * TPB + t;
        if (node < NB) {
            const float4* px = (const float4*)(x_b + node * 16);
            float acc[H];
            #pragma unroll
            for (int j = 0; j < H; ++j) acc[j] = sbb[j];
            #pragma unroll
            for (int c = 0; c < 4; ++c) {
                float4 q = px[c];
                float xs[4] = {q.x, q.y, q.z, q.w};
                #pragma unroll
                for (int u = 0; u < 4; ++u) {
                    int k = c * 4 + u;
                    #pragma unroll
                    for (int j = 0; j < H; ++j)
                        acc[j] = fmaf(xs[u], sWb[k][j], acc[j]);
                }
            }
            __half2 o[H / 2];
            #pragma unroll
            for (int j2 = 0; j2 < H / 2; ++j2)
                o[j2] = __floats2half2_rn(fmaxf(acc[2 * j2], 0.0f), fmaxf(acc[2 * j2 + 1], 0.0f));
            float4* dst = (float4*)(h_b16 + node * H);
            const float4* src = (const float4*)o;
            dst[0] = src[0]; dst[1] = src[1]; dst[2] = src[2]; dst[3] = src[3];
        } else if (node < (long long)NB + NR) {
            long long m = node - NB;
            const float4* px = (const float4*)(x_r + m * 8);
            float acc[H];
            #pragma unroll
            for (int j = 0; j < H; ++j) acc[j] = sbr[j];
            #pragma unroll
            for (int c = 0; c < 2; ++c) {
                float4 q = px[c];
                float xs[4] = {q.x, q.y, q.z, q.w};
                #pragma unroll
                for (int u = 0; u < 4; ++u) {
                    int k = c * 4 + u;
                    #pragma unroll
                    for (int j = 0; j < H; ++j)
                        acc[j] = fmaf(xs[u], sWr8[k][j], acc[j]);
                }
            }
            __half2 o[H / 2];
            #pragma unroll
            for (int j2 = 0; j2 < H / 2; ++j2)
                o[j2] = __floats2half2_rn(fmaxf(acc[2 * j2], 0.0f), fmaxf(acc[2 * j2 + 1], 0.0f));
            float4* dst = (float4*)(h_r16 + m * H);
            const float4* src = (const float4*)o;
            dst[0] = src[0]; dst[1] = src[1]; dst[2] = src[2]; dst[3] = src[3];
        }
    } else {
        // ---------------- place part (EPT=32, int4 loads, packed meta) ----------------
        __shared__ int lcnt[MAXBUCK];
        __shared__ int wbase[MAXBUCK];
        for (int i = t; i < MAXBUCK; i += TPB) lcnt[i] = 0;
        __syncthreads();

        long long e0 = (long long)(blockIdx.x - encBlocks) * (TPB * EPT);
        long long EA = (long long)E_RB + E_BB;
        long long rb4 = (long long)(E_RB >> 2);
        int meta[EPT];   // (bk<<20) | (loc<<7) | dloc ; -1 = invalid

        // pass 1: histogram + meta
        #pragma unroll
        for (int j = 0; j < EPT / 4; ++j) {
            long long i4 = (e0 >> 2) + (long long)j * TPB + t;
            long long eb = i4 << 2;
            int dd[4];
            if (eb + 3 < (long long)E_RB) {
                int4 dv = ((const int4*)dst_rb)[i4];
                dd[0] = dv.x; dd[1] = dv.y; dd[2] = dv.z; dd[3] = dv.w;
            } else if (eb >= (long long)E_RB && eb + 3 < EA) {
                int4 dv = ((const int4*)dst_bb)[i4 - rb4];
                dd[0] = dv.x + NB; dd[1] = dv.y + NB; dd[2] = dv.z + NB; dd[3] = dv.w + NB;
            } else {
                #pragma unroll
                for (int u = 0; u < 4; ++u) {
                    long long e = eb + u;
                    dd[u] = (e < E_RB) ? dst_rb[e] : (e < EA ? NB + dst_bb[e - E_RB] : -1);
                }
            }
            #pragma unroll
            for (int u = 0; u < 4; ++u) {
                if (dd[u] >= 0) {
                    int bk = dd[u] >> 7;
                    int loc = atomicAdd(&lcnt[bk], 1);
                    meta[j * 4 + u] = (bk << 20) | (loc << 7) | (dd[u] & 127);
                } else meta[j * 4 + u] = -1;
            }
        }
        __syncthreads();

        // flush: one global atomic per (WG, bucket)
        for (int i = t; i < NBUCK; i += TPB) {
            int c = lcnt[i];
            wbase[i] = c ? (i * CAP + atomicAdd(&gcurp[i * 16], c)) : 0;
        }
        __syncthreads();

        // pass 2: re-read src (L2-hot), write bins
        #pragma unroll
        for (int j = 0; j < EPT / 4; ++j) {
            long long i4 = (e0 >> 2) + (long long)j * TPB + t;
            long long eb = i4 << 2;
            int ss[4];
            if (eb + 3 < (long long)E_RB) {
                int4 sv = ((const int4*)src_rb)[i4];
                ss[0] = sv.x; ss[1] = sv.y; ss[2] = sv.z; ss[3] = sv.w;
            } else if (eb >= (long long)E_RB && eb + 3 < EA) {
                int4 sv = ((const int4*)src_bb)[i4 - rb4];
                ss[0] = sv.x; ss[1] = sv.y; ss[2] = sv.z; ss[3] = sv.w;
            } else {
                #pragma unroll
                for (int u = 0; u < 4; ++u) {
                    long long e = eb + u;
                    ss[u] = (e < E_RB) ? src_rb[e] : (e < EA ? (int)src_bb[e - E_RB] : 0);
                }
            }
            #pragma unroll
            for (int u = 0; u < 4; ++u) {
                int m = meta[j * 4 + u];
                if (m >= 0) {
                    int bk = (unsigned)m >> 20;
                    int loc = (m >> 7) & 0x1FFF;
                    int dloc = m & 127;
                    int gslot = wbase[bk] + loc;
                    if (gslot < (bk + 1) * CAP)          // overflow guard (never fires)
                        bins[gslot] = (ss[u] << 7) | dloc;
                }
            }
        }
    }
}

// ---------------- fused build+gather: int4 bins read, sort, unroll-8 gather ----------
__global__ void __launch_bounds__(TPB) buildgather_kernel(
        const __half* __restrict__ h_r16, const __half* __restrict__ h_b16,
        const int* __restrict__ bins, const int* __restrict__ gcurp,
        __half* __restrict__ mean16, int NB, int N2) {
    __shared__ int rawbuf[CAP];          // 8 KB  (bucket's packed edges)
    __shared__ int srcbuf[CAP];          // 8 KB  (slot-sorted srcs)
    __shared__ int lcnt[SLOTS];
    __shared__ int lbase[SLOTS];
    __shared__ int lcur[SLOTS];
    __shared__ int tmp[SLOTS];
    int t = threadIdx.x;
    int b = blockIdx.x;
    int start = b * CAP;                 // CAP multiple of 4 -> int4-aligned
    int n = gcurp[b * 16];               // relative count for this bucket
    if (n > CAP) n = CAP;

    if (t < SLOTS) lcnt[t] = 0;
    __syncthreads();

    // phase A: int4 read of bins into LDS + per-slot histogram
    {
        int n4 = n >> 2;
        const int4* bins4 = (const int4*)(bins + start);
        for (int i = t; i < n4; i += TPB) {
            int4 p = bins4[i];
            ((int4*)rawbuf)[i] = p;
            atomicAdd(&lcnt[p.x & 127], 1);
            atomicAdd(&lcnt[p.y & 127], 1);
            atomicAdd(&lcnt[p.z & 127], 1);
            atomicAdd(&lcnt[p.w & 127], 1);
        }
        for (int i = (n4 << 2) + t; i < n; i += TPB) {
            int packed = bins[start + i];
            rawbuf[i] = packed;
            atomicAdd(&lcnt[packed & 127], 1);
        }
    }
    __syncthreads();

    // phase B: exclusive scan of 128 slot counters
    if (t < SLOTS) tmp[t] = lcnt[t];
    __syncthreads();
    for (int off = 1; off < SLOTS; off <<= 1) {
        int x = (t >= off && t < SLOTS) ? tmp[t - off] : 0;
        __syncthreads();
        if (t < SLOTS) tmp[t] += x;
        __syncthreads();
    }
    if (t < SLOTS) { lbase[t] = tmp[t] - lcnt[t]; lcur[t] = tmp[t] - lcnt[t]; }
    __syncthreads();

    // phase C: LDS->LDS scatter, slot-sorted
    for (int i = t; i < n; i += TPB) {
        int packed = rawbuf[i];
        int slot = atomicAdd(&lcur[packed & 127], 1);
        srcbuf[slot] = packed >> 7;
    }
    __syncthreads();

    // phase D: gather; 16 groups of 16 lanes; lane owns channels {2l,2l+1}; 8/4/1 ILP
    int lane = t & 15, g = t >> 4;
    long long base_slot = (long long)b << 7;
    for (int sl = g; sl < SLOTS; sl += (TPB / 16)) {
        long long gd = base_slot + sl;
        if (gd >= N2) break;
        const __half* __restrict__ hs = (gd < NB) ? h_r16 : h_b16;
        int off = lbase[sl];
        int cnt = lcnt[sl];
        float ax = 0.0f, ay = 0.0f;
        int k = 0;
        for (; k + 8 <= cnt; k += 8) {
            int s[8];
            #pragma unroll
            for (int j = 0; j < 8; ++j) s[j] = srcbuf[off + k + j];
            float2 f[8];
            #pragma unroll
            for (int j = 0; j < 8; ++j)
                f[j] = __half22float2(*(const __half2*)(hs + (long long)s[j] * H + 2 * lane));
            #pragma unroll
            for (int j = 0; j < 8; ++j) { ax += f[j].x; ay += f[j].y; }
        }
        if (k + 4 <= cnt) {
            int s[4];
            #pragma unroll
            for (int j = 0; j < 4; ++j) s[j] = srcbuf[off + k + j];
            float2 f[4];
            #pragma unroll
            for (int j = 0; j < 4; ++j)
                f[j] = __half22float2(*(const __half2*)(hs + (long long)s[j] * H + 2 * lane));
            #pragma unroll
            for (int j = 0; j < 4; ++j) { ax += f[j].x; ay += f[j].y; }
            k += 4;
        }
        for (; k < cnt; ++k) {
            int s = srcbuf[off + k];
            float2 f = __half22float2(*(const __half2*)(hs + (long long)s * H + 2 * lane));
            ax += f.x; ay += f.y;
        }
        float inv = 1.0f / fmaxf((float)cnt, 1.0f);
        *(__half2*)(mean16 + gd * H + 2 * lane) = __floats2half2_rn(ax * inv, ay * inv);
    }
}

// ---------------- fused head (thread = node, fp16 inputs, W broadcast from LDS) ----------
__global__ void __launch_bounds__(TPB) head_kernel(
        const __half* __restrict__ h_b16,
        const __half* __restrict__ mean16,   // [2NB, H]
        const float* __restrict__ Wl_rb,
        const float* __restrict__ bl_rb,
        const float* __restrict__ Wl_bb,
        const float* __restrict__ bl_bb,
        const float* __restrict__ Wr_rb,
        const float* __restrict__ Wr_bb,
        const float* __restrict__ Wo,
        const float* __restrict__ bo,
        float* __restrict__ y, int N) {
    __shared__ float sWl_rb[H][H];
    __shared__ float sWl_bb[H][H];
    __shared__ float sWr[H][H];
    __shared__ float sbl[H];
    __shared__ float sWo[H];
    __shared__ float sbo;

    int t = threadIdx.x;
    for (int i = t; i < H * H; i += blockDim.x) {
        ((float*)sWl_rb)[i] = Wl_rb[i];
        ((float*)sWl_bb)[i] = Wl_bb[i];
        ((float*)sWr)[i]    = Wr_rb[i] + Wr_bb[i];
    }
    if (t < H) {
        sbl[t] = bl_rb[t] + bl_bb[t];
        sWo[t] = Wo[t];
    }
    if (t == 0) sbo = bo[0];
    __syncthreads();

    int node = blockIdx.x * TPB + t;
    if (node >= N) return;

    const float4* pr = (const float4*)(mean16 + (long long)node * H);
    const float4* pb = (const float4*)(mean16 + ((long long)N + node) * H);
    const float4* ph = (const float4*)(h_b16 + (long long)node * H);

    float acc[H];
    #pragma unroll
    for (int j = 0; j < H; ++j) acc[j] = sbl[j];

    #pragma unroll
    for (int c = 0; c < 4; ++c) {            // 8 k-values per chunk
        float4 qr = pr[c];
        float4 qb = pb[c];
        float4 qh = ph[c];
        const __half2* hr = (const __half2*)&qr;
        const __half2* hb = (const __half2*)&qb;
        const __half2* hh = (const __half2*)&qh;
        #pragma unroll
        for (int u = 0; u < 4; ++u) {
            float2 fr = __half22float2(hr[u]);
            float2 fb = __half22float2(hb[u]);
            float2 fh = __half22float2(hh[u]);
            int k0 = c * 8 + u * 2;
            #pragma unroll
            for (int j = 0; j < H; ++j) {
                acc[j] = fmaf(fr.x, sWl_rb[k0][j], acc[j]);
                acc[j] = fmaf(fb.x, sWl_bb[k0][j], acc[j]);
                acc[j] = fmaf(fh.x, sWr[k0][j], acc[j]);
                acc[j] = fmaf(fr.y, sWl_rb[k0 + 1][j], acc[j]);
                acc[j] = fmaf(fb.y, sWl_bb[k0 + 1][j], acc[j]);
                acc[j] = fmaf(fh.y, sWr[k0 + 1][j], acc[j]);
            }
        }
    }

    float out = 0.0f;
    #pragma unroll
    for (int j = 0; j < H; ++j)
        out = fmaf(fmaxf(acc[j], 0.0f), sWo[j], out);
    y[node] = out + sbo;
}

extern "C" void kernel_launch(void* const* d_in, const int* in_sizes, int n_in,
                              void* d_out, int out_size, void* d_ws, size_t ws_size,
                              hipStream_t stream) {
    const float* x_bridge = (const float*)d_in[0];
    const float* x_road   = (const float*)d_in[1];
    const int* src_rb = (const int*)d_in[4];
    const int* dst_rb = (const int*)d_in[5];
    const int* src_bb = (const int*)d_in[6];
    const int* dst_bb = (const int*)d_in[7];
    const float* W_enc_b = (const float*)d_in[8];
    const float* b_enc_b = (const float*)d_in[9];
    const float* W_enc_r = (const float*)d_in[10];
    const float* b_enc_r = (const float*)d_in[11];
    const float* Wl_rb = (const float*)d_in[15];
    const float* bl_rb = (const float*)d_in[16];
    const float* Wr_rb = (const float*)d_in[17];
    const float* Wl_bb = (const float*)d_in[18];
    const float* bl_bb = (const float*)d_in[19];
    const float* Wr_bb = (const float*)d_in[20];
    const float* Wo = (const float*)d_in[21];
    const float* bo = (const float*)d_in[22];
    float* y = (float*)d_out;

    const int NB = in_sizes[0] / 16;
    const int NR = in_sizes[1] / 8;
    const int E_RB = in_sizes[4];
    const int E_BB = in_sizes[6];
    const int N2 = 2 * NB;
    const long long E_ALL = (long long)E_RB + E_BB;
    const int NBUCK = (N2 + SLOTS - 1) / SLOTS;     // 1563

    // Workspace layout (~45 MB)
    char* wp = (char*)d_ws;
    __half* h_r16  = (__half*)wp; wp += (size_t)NR * H * sizeof(__half);
    __half* h_b16  = (__half*)wp; wp += (size_t)NB * H * sizeof(__half);
    __half* mean16 = (__half*)wp; wp += (size_t)N2 * H * sizeof(__half);
    int* bins  = (int*)wp;       wp += (size_t)NBUCK * CAP * sizeof(int);
    int* gcurp = (int*)wp;       wp += (size_t)NBUCK * 16 * sizeof(int);

    // zero the bucket cursors (relative counts), then run encoder || place
    hipMemsetAsync(gcurp, 0, (size_t)NBUCK * 16 * sizeof(int), stream);

    long long nodes = (long long)NB + NR;
    int encBlocks = (int)((nodes + TPB - 1) / TPB);                      // 1172
    int placeBlocks = (int)((E_ALL + (TPB * EPT) - 1) / (TPB * EPT));    // 184
    prep_kernel<<<encBlocks + placeBlocks, TPB, 0, stream>>>(
        x_bridge, x_road, W_enc_b, b_enc_b, W_enc_r, b_enc_r,
        h_b16, h_r16, NB, NR, encBlocks,
        src_rb, dst_rb, src_bb, dst_bb, gcurp, bins, E_RB, E_BB, NBUCK);

    // fused per-bucket slot-sort (LDS) + gather -> mean16
    buildgather_kernel<<<NBUCK, TPB, 0, stream>>>(h_r16, h_b16, bins, gcurp,
                                                  mean16, NB, N2);

    // fused head
    head_kernel<<<(NB + TPB - 1) / TPB, TPB, 0, stream>>>(h_b16, mean16,
                                                  Wl_rb, bl_rb, Wl_bb, bl_bb,
                                                  Wr_rb, Wr_bb, Wo, bo, y, NB);
}